// Round 9
// baseline (224.168 us; speedup 1.0000x reference)
//
#include <hip/hip_runtime.h>
#include <hip/hip_fp16.h>

#define N_NODES 4096
#define EPS 0.005f
#define TH0 0.4f
#define TH1 0.24f
#define TH2 0.144f
#define TH3 0.0864f
#define JTILE 256
#define NTILES (N_NODES / JTILE)
#define RCAP 80      // fixed per-row slot capacity (mean deg 32, P(>80)~1e-13)
#define CPAD 16      // one counter per 64B line -> no cross-XCD line ping-pong

typedef float v4f __attribute__((ext_vector_type(4)));
typedef unsigned int u32x2 __attribute__((ext_vector_type(2)));
typedef unsigned int u32x4 __attribute__((ext_vector_type(4)));

// ws layout (byte offsets):
//   0      counts int[4096*16]         256KB \ one contiguous memset (2816KB)
//   256K   pairs  int2[4096*RCAP]      2.5MB / pads col=0,val=0 -> fma no-op
//   4M     m2     f16[N*N]             32MB dense thresholded A@A
// R8 post-mortem: out_kernel is MEMORY-CONCURRENCY capped (VALUBusy ~35% at
// every occupancy; halving VALU gained only 4%). Throughput = C/latency with
// C ~ few KB/CU -> the only lever is lower latency: make gathers L2-hit.
// JTILE=256 -> 2MB slice/XCD (R4 proved FETCH drops to ~compulsory) and
// 16 edges/iter (R4's regression was keeping 8/iter: same latency-slots for
// half the columns). Time-partition: tiles 0-7 then 8-15.

static __device__ __forceinline__ unsigned short f2h(float f) {
    return __half_as_ushort(__float2half(f));  // RNE
}

// one pass: bin edges into fixed-stride packed (col,val) slots
__global__ void scatter_kernel(const int* __restrict__ idx,
                               const float* __restrict__ attr, int E,
                               int* __restrict__ counts, int2* __restrict__ pairs) {
    int e = blockIdx.x * blockDim.x + threadIdx.x;
    if (e < E) {
        int s = idx[e];
        int d = idx[e + E];
        float a = attr[e];
        int pos = atomicAdd(&counts[s * CPAD], 1);
        if (pos < RCAP) pairs[s * RCAP + pos] = make_int2(d, __float_as_int(a));
    }
}

// M2 = thr(A@A) f16. One block per row, full-row 16KB LDS accumulator.
__global__ __launch_bounds__(256)
void m2_kernel(const int* __restrict__ counts, const int2* __restrict__ pairs,
               unsigned short* __restrict__ m2) {
    __shared__ float acc[N_NODES];
    __shared__ int   kcol[RCAP];
    __shared__ float kval[RCAP];
    __shared__ int   kcnt[RCAP];
    int i = blockIdx.x;
    int t = threadIdx.x;
    float4 z = make_float4(0.f, 0.f, 0.f, 0.f);
    for (int j4 = t; j4 < N_NODES / 4; j4 += 256) ((float4*)acc)[j4] = z;
    int cnt = min(counts[i * CPAD], RCAP);
    if (t < cnt) {
        int2 p = pairs[i * RCAP + t];
        kcol[t] = p.x;
        kval[t] = __int_as_float(p.y);
        kcnt[t] = min(counts[p.x * CPAD], RCAP);
    }
    __syncthreads();
    int gid = t >> 3, gl = t & 7;            // 32 groups x 8 lanes
    int2 zp = make_int2(0, 0);
    for (int q = gid; q < cnt; q += 32) {
        float a = kval[q];
        int fb = kcol[q] * RCAP;
        int fn = kcnt[q];
        for (int f0 = gl; f0 < fn; f0 += 32) {
            int i1 = f0 + 8, i2 = f0 + 16, i3 = f0 + 24;
            int2 p0 = pairs[fb + f0];
            int2 p1 = (i1 < fn) ? pairs[fb + i1] : zp;
            int2 p2 = (i2 < fn) ? pairs[fb + i2] : zp;
            int2 p3 = (i3 < fn) ? pairs[fb + i3] : zp;
            unsafeAtomicAdd(&acc[p0.x], a * __int_as_float(p0.y));
            unsafeAtomicAdd(&acc[p1.x], a * __int_as_float(p1.y));
            unsafeAtomicAdd(&acc[p2.x], a * __int_as_float(p2.y));
            unsafeAtomicAdd(&acc[p3.x], a * __int_as_float(p3.y));
        }
    }
    __syncthreads();
    size_t rb = (size_t)i * N_NODES;
    for (int j4 = t; j4 < N_NODES / 4; j4 += 256) {
        float4 v = ((const float4*)acc)[j4];
        ushort4 r;
        r.x = (v.x >= EPS) ? f2h(v.x) : (unsigned short)0;
        r.y = (v.y >= EPS) ? f2h(v.y) : (unsigned short)0;
        r.z = (v.z >= EPS) ? f2h(v.z) : (unsigned short)0;
        r.w = (v.w >= EPS) ? f2h(v.w) : (unsigned short)0;
        ((ushort4*)(m2 + rb))[j4] = r;
    }
}

// out[i, jb:jb+256] = TH0*P0 + TH1*A + TH2*M2 + TH3*thr(A @ M2)  — fused.
// 2 waves/block = 2 rows; wave-private LDS strips; 4 cols/lane (8B gathers);
// 16 edges per main iteration (64 fma_mix in flight over 16 gathers), 8-edge
// tail when cnt8%16==8 (slots stay < RCAP: zero-pads only, never garbage).
#define MIX2(uu_word, aclo, achi, aa)                                          \
    asm("v_fma_mix_f32 %0, %1, %2, %0 op_sel_hi:[0,1,0]"                       \
        : "+v"(aclo) : "v"(aa), "v"(uu_word));                                 \
    asm("v_fma_mix_f32 %0, %1, %2, %0 op_sel:[0,1,0] op_sel_hi:[0,1,0]"        \
        : "+v"(achi) : "v"(aa), "v"(uu_word));

#define MIX4(uu, aa)                                                           \
    MIX2(uu.x, ac0, ac1, aa) MIX2(uu.y, ac2, ac3, aa)

// extract 2 (k,a) from one int4 quad
#define EX2(q, klo, alo, khi, ahi)                                             \
    klo = __builtin_amdgcn_readfirstlane(q.x); alo = __int_as_float(q.y);      \
    khi = __builtin_amdgcn_readfirstlane(q.z); ahi = __int_as_float(q.w);

#define GATH(k, u)  u = *(const u32x2*)(m2l + (size_t)k * N_NODES);

__global__ __launch_bounds__(128)
void out_kernel(const int* __restrict__ counts, const int2* __restrict__ pairs,
                const unsigned short* __restrict__ m2,
                float* __restrict__ out) {
    __shared__ float ap[2][JTILE];
    int lin = blockIdx.x;
    int tile = (lin & 7) | ((lin >> 14) << 3);   // 0-7 first half, 8-15 second
    int jb = tile * JTILE;
    int t = threadIdx.x;
    int w = t >> 6, lane = t & 63;
    int i = 2 * ((lin >> 3) & 2047) + w;
    float* apw = ap[w];
    ((float4*)apw)[lane] = make_float4(0.f, 0.f, 0.f, 0.f);  // 256 floats/wave
    int cnt = min(counts[i * CPAD], RCAP);
    const int2* pi = pairs + i * RCAP;
    // P0 + A scatter into private strip (dups accumulate; cnt excludes pads)
    for (int e = lane; e < cnt; e += 64) {
        int2 p = pi[e];
        int cl = p.x - jb;
        if ((unsigned)cl < (unsigned)JTILE)
            unsafeAtomicAdd(&apw[cl], TH0 + TH1 * __int_as_float(p.y));
    }
    int cnt8 = (cnt + 7) & ~7;
    const unsigned short* m2l = m2 + jb + 4 * lane;
    const int4* pi4 = (const int4*)pi;
    float ac0 = 0.f, ac1 = 0.f, ac2 = 0.f, ac3 = 0.f;

    int e = 0;
    // main: 16 edges per iteration
    for (; e + 16 <= cnt8; e += 16) {
        int4 q0 = pi4[(e >> 1) + 0], q1 = pi4[(e >> 1) + 1];
        int4 q2 = pi4[(e >> 1) + 2], q3 = pi4[(e >> 1) + 3];
        int4 q4 = pi4[(e >> 1) + 4], q5 = pi4[(e >> 1) + 5];
        int4 q6 = pi4[(e >> 1) + 6], q7 = pi4[(e >> 1) + 7];
        int k0, k1, k2, k3, k4, k5, k6, k7, k8, k9, kA, kB, kC, kD, kE, kF;
        float a0, a1, a2, a3, a4, a5, a6, a7, a8, a9, aA, aB, aC, aD, aE, aF;
        EX2(q0, k0, a0, k1, a1) EX2(q1, k2, a2, k3, a3)
        EX2(q2, k4, a4, k5, a5) EX2(q3, k6, a6, k7, a7)
        EX2(q4, k8, a8, k9, a9) EX2(q5, kA, aA, kB, aB)
        EX2(q6, kC, aC, kD, aD) EX2(q7, kE, aE, kF, aF)
        u32x2 u0, u1, u2, u3, u4, u5, u6, u7, u8, u9, uA, uB, uC, uD, uE, uF;
        GATH(k0, u0) GATH(k1, u1) GATH(k2, u2) GATH(k3, u3)
        GATH(k4, u4) GATH(k5, u5) GATH(k6, u6) GATH(k7, u7)
        GATH(k8, u8) GATH(k9, u9) GATH(kA, uA) GATH(kB, uB)
        GATH(kC, uC) GATH(kD, uD) GATH(kE, uE) GATH(kF, uF)
        MIX4(u0, a0) MIX4(u1, a1) MIX4(u2, a2) MIX4(u3, a3)
        MIX4(u4, a4) MIX4(u5, a5) MIX4(u6, a6) MIX4(u7, a7)
        MIX4(u8, a8) MIX4(u9, a9) MIX4(uA, aA) MIX4(uB, aB)
        MIX4(uC, aC) MIX4(uD, aD) MIX4(uE, aE) MIX4(uF, aF)
    }
    // tail: one 8-edge batch (slots < cnt8 <= RCAP: zero-pads only)
    if (e < cnt8) {
        int4 q0 = pi4[(e >> 1) + 0], q1 = pi4[(e >> 1) + 1];
        int4 q2 = pi4[(e >> 1) + 2], q3 = pi4[(e >> 1) + 3];
        int k0, k1, k2, k3, k4, k5, k6, k7;
        float a0, a1, a2, a3, a4, a5, a6, a7;
        EX2(q0, k0, a0, k1, a1) EX2(q1, k2, a2, k3, a3)
        EX2(q2, k4, a4, k5, a5) EX2(q3, k6, a6, k7, a7)
        u32x2 u0, u1, u2, u3, u4, u5, u6, u7;
        GATH(k0, u0) GATH(k1, u1) GATH(k2, u2) GATH(k3, u3)
        GATH(k4, u4) GATH(k5, u5) GATH(k6, u6) GATH(k7, u7)
        MIX4(u0, a0) MIX4(u1, a1) MIX4(u2, a2) MIX4(u3, a3)
        MIX4(u4, a4) MIX4(u5, a5) MIX4(u6, a6) MIX4(u7, a7)
    }

    // epilogue: private strip + TH2*m2[i] + TH3*thr(acc)
    u32x2 um = *(const u32x2*)(m2 + (size_t)i * N_NODES + jb + 4 * lane);
    unsigned ux = um.x, uy = um.y;
    __half2 hx = *(__half2*)&ux, hy = *(__half2*)&uy;
    float4 p0 = ((const float4*)apw)[lane];
    v4f r0;
    r0.x = p0.x + TH2 * __low2float(hx)  + TH3 * ((ac0 >= EPS) ? ac0 : 0.0f);
    r0.y = p0.y + TH2 * __high2float(hx) + TH3 * ((ac1 >= EPS) ? ac1 : 0.0f);
    r0.z = p0.z + TH2 * __low2float(hy)  + TH3 * ((ac2 >= EPS) ? ac2 : 0.0f);
    r0.w = p0.w + TH2 * __high2float(hy) + TH3 * ((ac3 >= EPS) ? ac3 : 0.0f);
    float* o = out + (size_t)i * N_NODES + jb + 4 * lane;
    __builtin_nontemporal_store(r0, (v4f*)o);
}

extern "C" void kernel_launch(void* const* d_in, const int* in_sizes, int n_in,
                              void* d_out, int out_size, void* d_ws, size_t ws_size,
                              hipStream_t stream) {
    const int* idx = (const int*)d_in[1];     // [2,E] flat: src then dst
    const float* attr = (const float*)d_in[2];
    int E = in_sizes[1] / 2;

    char* ws = (char*)d_ws;
    int*  counts = (int*)(ws);
    int2* pairs  = (int2*)(ws + (256 << 10));
    unsigned short* m2 = (unsigned short*)(ws + (4 << 20));
    float* out   = (float*)d_out;

    // counts (padded) + pairs contiguous: one memset
    (void)hipMemsetAsync(ws, 0,
                         (256 << 10) + N_NODES * RCAP * sizeof(int2), stream);
    scatter_kernel<<<(E + 255) / 256, 256, 0, stream>>>(idx, attr, E, counts, pairs);
    m2_kernel<<<N_NODES, 256, 0, stream>>>(counts, pairs, m2);
    out_kernel<<<(N_NODES / 2) * NTILES, 128, 0, stream>>>(counts, pairs, m2, out);
}